// Round 4
// baseline (339.347 us; speedup 1.0000x reference)
//
#include <hip/hip_runtime.h>

// PairwiseScore round 4: counted-vmcnt software pipeline (raw s_barrier, never
// drain to 0), 3-buffer LDS rotation, column-split waves.
//   h1 = relu(gi@W1a + gj@W1b + (gi.gj)@W1c + b1)   [A/B precomp per mention]
//   out = relu(h1@W2 + b2) @ W3 + b3
// Shapes: M=10000, D=1200(->1216), P=2000, K=50, H=150(->160), NP=98725.

typedef __attribute__((ext_vector_type(8))) short short8;
typedef __attribute__((ext_vector_type(4))) float f32x4;

constexpr int DP    = 1216;      // padded G_DIM (38*32)
constexpr int HPAD  = 160;       // padded hidden
constexpr int NKC   = 38;        // K-chunks of 32 over DP
constexpr int NKC2  = 5;         // K-chunks of 32 over HPAD
constexpr int WCHU  = 10240;     // ushorts per W chunk image (hi 5120 + lo 5120)
constexpr int ROWS1 = 96;        // k_pair rows/block (2 rw x 3 rt x 16)
constexpr int ROWS2 = 128;       // k_mlp rows/block  (2 rw x 4 rt x 16)
constexpr int RPC   = 128;       // k_precomp rows/block

__device__ __forceinline__ ushort bf16_rne(float x) {
  uint u = __float_as_uint(x);
  u += 0x7FFFu + ((u >> 16) & 1u);
  return (ushort)(u >> 16);
}
__device__ __forceinline__ float bf16f(ushort h) {
  return __uint_as_float((uint)h << 16);
}
__device__ __forceinline__ f32x4 mfma16(short8 a, short8 b, f32x4 c) {
  return __builtin_amdgcn_mfma_f32_16x16x32_bf16(a, b, c, 0, 0, 0);
}
__device__ __forceinline__ void g2lds16(const void* g, void* l) {
  __builtin_amdgcn_global_load_lds(
      (const __attribute__((address_space(1))) void*)g,
      (__attribute__((address_space(3))) void*)l, 16, 0, 0);
}
// stage one 20480B W-chunk image: 4 waves x 5 issues x 1024B (linear copy)
__device__ __forceinline__ void stage_chunk(const ushort* gsrc, ushort* lbuf,
                                            int w, int lane) {
  const char* g = (const char*)gsrc + w * 5120 + lane * 16;
  char* l = (char*)lbuf + w * 5120;
#pragma unroll
  for (int q = 0; q < 5; ++q) g2lds16(g + q * 1024, l + q * 1024);
}
// split product gi*gj (8 elems) into bf16 hi (trunc) + lo (trunc residual)
__device__ __forceinline__ void splitp(float4 a0, float4 a1, float4 b0,
                                       float4 b1, short8& hi, short8& lo) {
  float p[8] = {a0.x * b0.x, a0.y * b0.y, a0.z * b0.z, a0.w * b0.w,
                a1.x * b1.x, a1.y * b1.y, a1.z * b1.z, a1.w * b1.w};
  uint h[4], l[4];
#pragma unroll
  for (int e = 0; e < 4; ++e) {
    uint u0 = __float_as_uint(p[2 * e]), u1 = __float_as_uint(p[2 * e + 1]);
    float r0 = p[2 * e] - __uint_as_float(u0 & 0xffff0000u);
    float r1 = p[2 * e + 1] - __uint_as_float(u1 & 0xffff0000u);
    h[e] = __builtin_amdgcn_perm(u1, u0, 0x07060302u);
    l[e] = __builtin_amdgcn_perm(__float_as_uint(r1), __float_as_uint(r0),
                                 0x07060302u);
  }
  uint4 hu = make_uint4(h[0], h[1], h[2], h[3]);
  uint4 lu = make_uint4(l[0], l[1], l[2], l[3]);
  hi = *(short8*)&hu; lo = *(short8*)&lu;
}
__device__ __forceinline__ void split1(const float* a, short8& hi, short8& lo) {
  const float4 a0 = *(const float4*)a, a1 = *(const float4*)(a + 4);
  float p[8] = {a0.x, a0.y, a0.z, a0.w, a1.x, a1.y, a1.z, a1.w};
  uint h[4], l[4];
#pragma unroll
  for (int e = 0; e < 4; ++e) {
    uint u0 = __float_as_uint(p[2 * e]), u1 = __float_as_uint(p[2 * e + 1]);
    float r0 = p[2 * e] - __uint_as_float(u0 & 0xffff0000u);
    float r1 = p[2 * e + 1] - __uint_as_float(u1 & 0xffff0000u);
    h[e] = __builtin_amdgcn_perm(u1, u0, 0x07060302u);
    l[e] = __builtin_amdgcn_perm(__float_as_uint(r1), __float_as_uint(r0),
                                 0x07060302u);
  }
  uint4 hu = make_uint4(h[0], h[1], h[2], h[3]);
  uint4 lu = make_uint4(l[0], l[1], l[2], l[3]);
  hi = *(short8*)&hu; lo = *(short8*)&lu;
}
__device__ __forceinline__ void pair_ij(int r, int K, int NP, int& i, int& j) {
  if (r >= NP) { i = 1; j = 0; return; }
  const int T = K * (K - 1) / 2;
  if (r < T) {
    int ii = (int)((1.0f + sqrtf(1.0f + 8.0f * (float)r)) * 0.5f);
    while (ii * (ii - 1) / 2 > r) --ii;
    while ((ii + 1) * ii / 2 <= r) ++ii;
    i = ii; j = r - ii * (ii - 1) / 2;
  } else {
    const int rp = r - T, q = rp / K;
    i = K + q; j = i - K + (rp - q * K);
  }
}

// ---------- k_prep: W1/W2 -> chunk-major, bf16 hi/lo, XOR-swizzled image ----------
__global__ void k_prep(const float* __restrict__ W1, const float* __restrict__ W2,
                       ushort* __restrict__ W1ch, ushort* __restrict__ W2ch) {
  const int N1 = 3 * NKC * HPAD * 32;
  int idx = blockIdx.x * 256 + threadIdx.x;
  if (idx < N1) {
    int s = idx / (NKC * HPAD * 32), r1 = idx % (NKC * HPAD * 32);
    int c = r1 / (HPAD * 32), r2 = r1 % (HPAD * 32);
    int col = r2 >> 5, kk = r2 & 31;
    int k = c * 32 + kk;
    float v = (k < 1200 && col < 150) ? W1[((size_t)s * 1200 + k) * 150 + col] : 0.f;
    ushort h = bf16_rne(v);
    ushort l = bf16_rne(v - bf16f(h));
    size_t base = (size_t)(s * NKC + c) * WCHU;
    int i0 = (col * 32 + kk) ^ ((col & 7) << 3);
    W1ch[base + i0] = h;
    W1ch[base + i0 + 5120] = l;
  } else {
    idx -= N1;
    if (idx < NKC2 * HPAD * 32) {
      int c = idx / (HPAD * 32), r2 = idx % (HPAD * 32);
      int col = r2 >> 5, kk = r2 & 31;
      int k = c * 32 + kk;
      float v = (k < 150 && col < 150) ? W2[(size_t)k * 150 + col] : 0.f;
      ushort h = bf16_rne(v);
      ushort l = bf16_rne(v - bf16f(h));
      size_t base = (size_t)c * WCHU;
      int i0 = (col * 32 + kk) ^ ((col & 7) << 3);
      W2ch[base + i0] = h;
      W2ch[base + i0 + 5120] = l;
    }
  }
}

// ---------- k_gather: G = mention_reprs[pruned_idx], pad 1200->1216 ----------
__global__ void k_gather(const float* __restrict__ M, const int* __restrict__ pidx,
                         float* __restrict__ G) {
  const int i = blockIdx.x;
  const int r = pidx[i];
  const float4* src = reinterpret_cast<const float4*>(M + (size_t)r * 1200);
  float4* dst = reinterpret_cast<float4*>(G + (size_t)i * DP);
  for (int t = threadIdx.x; t < DP / 4; t += blockDim.x)
    dst[t] = (t < 300) ? src[t] : make_float4(0.f, 0.f, 0.f, 0.f);
}

// ---------- k_precomp: AB[slab][r][col] = G[r]@W1slab (+b1 if slab0) ----------
__global__ __launch_bounds__(256, 3) void k_precomp(
    const float* __restrict__ G, const ushort* __restrict__ W1ch,
    const float* __restrict__ b1, float* __restrict__ AB, int P) {
  __shared__ __align__(16) ushort Wb0[WCHU];
  __shared__ __align__(16) ushort Wb1[WCHU];
  const int tid = threadIdx.x, lane = tid & 63, w = tid >> 6;
  const int l15 = lane & 15, kb = lane >> 4;
  const int r0 = blockIdx.x * RPC;
  const int slab = blockIdx.y;
  const ushort* wsrc = W1ch + (size_t)slab * NKC * WCHU;

  const int row0 = min(r0 + w * 32 + l15, P - 1);
  const int row1 = min(r0 + w * 32 + 16 + l15, P - 1);
  const float* g0 = G + (size_t)row0 * DP + kb * 8;
  const float* g1 = G + (size_t)row1 * DP + kb * 8;
  const int lbase = (l15 * 32 + kb * 8) ^ ((l15 & 7) << 3);

  f32x4 acc[2][10];
#pragma unroll
  for (int a = 0; a < 2; ++a)
#pragma unroll
    for (int b = 0; b < 10; ++b) acc[a][b] = (f32x4)(0.f);

  stage_chunk(wsrc, Wb0, w, lane);
  short8 ah0, al0, ah1, al1;
  split1(g0, ah0, al0);
  split1(g1, ah1, al1);

#pragma unroll 2
  for (int c = 0; c < NKC; ++c) {
    __syncthreads();
    if (c < NKC - 1)
      stage_chunk(wsrc + (size_t)(c + 1) * WCHU, (c & 1) ? Wb0 : Wb1, w, lane);
    const ushort* wb = (c & 1) ? Wb1 : Wb0;
#pragma unroll
    for (int ct = 0; ct < 10; ++ct) {
      const short8 bh = *(const short8*)&wb[lbase + ct * 512];
      const short8 bl = *(const short8*)&wb[lbase + ct * 512 + 5120];
      acc[0][ct] = mfma16(ah0, bh, acc[0][ct]);
      acc[1][ct] = mfma16(ah1, bh, acc[1][ct]);
      acc[0][ct] = mfma16(al0, bh, acc[0][ct]);
      acc[1][ct] = mfma16(al1, bh, acc[1][ct]);
      acc[0][ct] = mfma16(ah0, bl, acc[0][ct]);
      acc[1][ct] = mfma16(ah1, bl, acc[1][ct]);
    }
    if (c < NKC - 1) {
      split1(g0 + (c + 1) * 32, ah0, al0);
      split1(g1 + (c + 1) * 32, ah1, al1);
    }
  }
  float* outp = AB + (size_t)slab * P * HPAD;
#pragma unroll
  for (int rt = 0; rt < 2; ++rt)
#pragma unroll
    for (int q = 0; q < 4; ++q) {
      const int r = r0 + w * 32 + rt * 16 + kb * 4 + q;
      if (r < P) {
#pragma unroll
        for (int ct = 0; ct < 10; ++ct) {
          const int col = ct * 16 + l15;
          float v = acc[rt][ct][q];
          if (slab == 0 && col < 150) v += b1[col];
          outp[(size_t)r * HPAD + col] = v;
        }
      }
    }
}

// ---------- k_pair_l1: bilinear pair GEMM -> H1 bf16, counted-vmcnt pipeline ----------
__global__ __launch_bounds__(256, 2) void k_pair_l1(
    const float* __restrict__ G, const ushort* __restrict__ W1ch,
    const float* __restrict__ AB, ushort* __restrict__ H1,
    int P, int K, int NP) {
  __shared__ __align__(16) ushort B3[3][WCHU];   // 61440 B
  const int tid = threadIdx.x, lane = tid & 63, w = tid >> 6;
  const int l15 = lane & 15, kb = lane >> 4;
  const int rw = w >> 1, cw = w & 1;
  const int r0 = blockIdx.x * ROWS1;
  const ushort* wsrc = W1ch + (size_t)2 * NKC * WCHU;  // slab 2 = W1c

  const float *pgi[3], *pgj[3];
#pragma unroll
  for (int rt = 0; rt < 3; ++rt) {
    int i, j;
    pair_ij(r0 + rw * 48 + rt * 16 + l15, K, NP, i, j);
    pgi[rt] = G + (size_t)i * DP + kb * 8;
    pgj[rt] = G + (size_t)j * DP + kb * 8;
  }
  const int lswz = (l15 * 32 + kb * 8) ^ ((l15 & 7) << 3);
  const int ctg0 = cw * 5;

  f32x4 acc[3][5];
#pragma unroll
  for (int a = 0; a < 3; ++a)
#pragma unroll
    for (int b = 0; b < 5; ++b) acc[a][b] = (f32x4)(0.f);

  // prologue: DMA chunk0,1; fence; G-regs chunk0.  Queue: [DMA0:5][DMA1:5][G0:12]
  stage_chunk(wsrc, &B3[0][0], w, lane);
  stage_chunk(wsrc + WCHU, &B3[1][0], w, lane);
  asm volatile("" ::: "memory");
  float4 cgi[6], cgj[6], ngi[6], ngj[6];
#pragma unroll
  for (int rt = 0; rt < 3; ++rt) {
    cgi[2 * rt]     = *(const float4*)(pgi[rt]);
    cgi[2 * rt + 1] = *(const float4*)(pgi[rt] + 4);
    cgj[2 * rt]     = *(const float4*)(pgj[rt]);
    cgj[2 * rt + 1] = *(const float4*)(pgj[rt] + 4);
  }
  int cb = 0, tb = 2;

  // per iter: newer-than-DMA(c) = G(c):12 + DMA(c+1):5 = 17 -> vmcnt(17)
#define P_ITER(CI, UI, UJ, LI, LJ)                                             \
  do {                                                                         \
    __builtin_amdgcn_sched_barrier(0);                                         \
    asm volatile("s_waitcnt vmcnt(17)" ::: "memory");                          \
    __builtin_amdgcn_s_barrier();                                              \
    __builtin_amdgcn_sched_barrier(0);                                         \
    short8 ah[3], al[3];                                                       \
    _Pragma("unroll")                                                          \
    for (int rt = 0; rt < 3; ++rt)                                             \
      splitp(UI[2 * rt], UI[2 * rt + 1], UJ[2 * rt], UJ[2 * rt + 1],           \
             ah[rt], al[rt]);                                                  \
    {                                                                          \
      const int cn = (CI) + 1 < NKC ? (CI) + 1 : NKC - 1;                      \
      _Pragma("unroll")                                                        \
      for (int rt = 0; rt < 3; ++rt) {                                         \
        LI[2 * rt]     = *(const float4*)(pgi[rt] + (size_t)cn * 32);          \
        LI[2 * rt + 1] = *(const float4*)(pgi[rt] + (size_t)cn * 32 + 4);      \
        LJ[2 * rt]     = *(const float4*)(pgj[rt] + (size_t)cn * 32);          \
        LJ[2 * rt + 1] = *(const float4*)(pgj[rt] + (size_t)cn * 32 + 4);      \
      }                                                                        \
      const int sc = (CI) + 2 < NKC ? (CI) + 2 : NKC - 1;                      \
      stage_chunk(wsrc + (size_t)sc * WCHU, &B3[tb][0], w, lane);              \
    }                                                                          \
    __builtin_amdgcn_sched_barrier(0);                                         \
    {                                                                          \
      const ushort* wb = &B3[cb][0];                                           \
      _Pragma("unroll")                                                        \
      for (int ct = 0; ct < 5; ++ct) {                                         \
        const int ob = (ctg0 + ct) * 512 + lswz;                               \
        const short8 bh = *(const short8*)&wb[ob];                             \
        const short8 bl = *(const short8*)&wb[ob + 5120];                      \
        _Pragma("unroll")                                                      \
        for (int rt = 0; rt < 3; ++rt) {                                       \
          acc[rt][ct] = mfma16(ah[rt], bh, acc[rt][ct]);                       \
          acc[rt][ct] = mfma16(al[rt], bh, acc[rt][ct]);                       \
          acc[rt][ct] = mfma16(ah[rt], bl, acc[rt][ct]);                       \
        }                                                                      \
      }                                                                        \
    }                                                                          \
    cb = cb == 2 ? 0 : cb + 1;                                                 \
    tb = tb == 2 ? 0 : tb + 1;                                                 \
  } while (0)

  for (int c = 0; c < NKC; c += 2) {
    P_ITER(c, cgi, cgj, ngi, ngj);
    P_ITER(c + 1, ngi, ngj, cgi, cgj);
  }
#undef P_ITER

  // epilogue: h1 = relu(acc + A[i] + B[j]) -> H1 bf16
  __syncthreads();
  int* tI = (int*)&B3[0][0];
  int* tJ = tI + ROWS1;
  if (tid < ROWS1) {
    int i, j;
    pair_ij(r0 + tid, K, NP, i, j);
    tI[tid] = i; tJ[tid] = j;
  }
  __syncthreads();
#pragma unroll
  for (int rt = 0; rt < 3; ++rt)
#pragma unroll
    for (int q = 0; q < 4; ++q) {
      const int rr = rw * 48 + rt * 16 + kb * 4 + q;
      const float* Ar = AB + (size_t)tI[rr] * HPAD;
      const float* Br = AB + ((size_t)P + tJ[rr]) * HPAD;
      ushort* hrow = H1 + (size_t)(r0 + rr) * HPAD;
#pragma unroll
      for (int ct = 0; ct < 5; ++ct) {
        const int col = (ctg0 + ct) * 16 + l15;
        const float v = acc[rt][ct][q] + Ar[col] + Br[col];
        hrow[col] = bf16_rne(fmaxf(v, 0.f));
      }
    }
}

// ---------- k_mlp: out = relu(H1@W2 + b2) @ W3 + b3, same pipeline ----------
__global__ __launch_bounds__(256, 2) void k_mlp(
    const ushort* __restrict__ H1, const ushort* __restrict__ W2ch,
    const float* __restrict__ b2, const float* __restrict__ W3,
    const float* __restrict__ b3, float* __restrict__ out, int NP) {
  __shared__ __align__(16) ushort B3[3][WCHU];
  const int tid = threadIdx.x, lane = tid & 63, w = tid >> 6;
  const int l15 = lane & 15, kb = lane >> 4;
  const int rw = w >> 1, cw = w & 1;
  const int r0 = blockIdx.x * ROWS2;
  const int lswz = (l15 * 32 + kb * 8) ^ ((l15 & 7) << 3);
  const int ctg0 = cw * 5;

  float b2v[5], w3v[5];
#pragma unroll
  for (int ct = 0; ct < 5; ++ct) {
    const int col = (ctg0 + ct) * 16 + l15;
    b2v[ct] = (col < 150) ? b2[col] : 0.f;
    w3v[ct] = (col < 150) ? W3[col] : 0.f;
  }
  const float b3v = b3[0];
  asm volatile("s_waitcnt vmcnt(0)" ::: "memory");

  const ushort* hp[4];
#pragma unroll
  for (int rt = 0; rt < 4; ++rt)
    hp[rt] = H1 + (size_t)(r0 + rw * 64 + rt * 16 + l15) * HPAD + kb * 8;

  f32x4 acc[4][5];
#pragma unroll
  for (int a = 0; a < 4; ++a)
#pragma unroll
    for (int b = 0; b < 5; ++b) acc[a][b] = (f32x4)(0.f);

  stage_chunk(W2ch, &B3[0][0], w, lane);
  stage_chunk(W2ch + WCHU, &B3[1][0], w, lane);
  asm volatile("" ::: "memory");
  short8 ca[4], na[4];
#pragma unroll
  for (int rt = 0; rt < 4; ++rt) ca[rt] = *(const short8*)(hp[rt]);
  int cb = 0, tb = 2;

  // newer-than-DMA(c) = G(c):4 + DMA(c+1):5 = 9 -> vmcnt(9)
#define M_ITER(CI, UA, LA)                                                     \
  do {                                                                         \
    __builtin_amdgcn_sched_barrier(0);                                         \
    asm volatile("s_waitcnt vmcnt(9)" ::: "memory");                           \
    __builtin_amdgcn_s_barrier();                                              \
    __builtin_amdgcn_sched_barrier(0);                                         \
    {                                                                          \
      const int cn = (CI) + 1 < NKC2 ? (CI) + 1 : NKC2 - 1;                    \
      _Pragma("unroll")                                                        \
      for (int rt = 0; rt < 4; ++rt)                                           \
        LA[rt] = *(const short8*)(hp[rt] + (size_t)cn * 32);                   \
      const int sc = (CI) + 2 < NKC2 ? (CI) + 2 : NKC2 - 1;                    \
      stage_chunk(W2ch + (size_t)sc * WCHU, &B3[tb][0], w, lane);              \
    }                                                                          \
    __builtin_amdgcn_sched_barrier(0);                                         \
    {                                                                          \
      const ushort* wb = &B3[cb][0];                                           \
      _Pragma("unroll")                                                        \
      for (int ct = 0; ct < 5; ++ct) {                                         \
        const int ob = (ctg0 + ct) * 512 + lswz;                               \
        const short8 bh = *(const short8*)&wb[ob];                             \
        const short8 bl = *(const short8*)&wb[ob + 5120];                      \
        _Pragma("unroll")                                                      \
        for (int rt = 0; rt < 4; ++rt) {                                       \
          acc[rt][ct] = mfma16(UA[rt], bh, acc[rt][ct]);                       \
          acc[rt][ct] = mfma16(UA[rt], bl, acc[rt][ct]);                       \
        }                                                                      \
      }                                                                        \
    }                                                                          \
    cb = cb == 2 ? 0 : cb + 1;                                                 \
    tb = tb == 2 ? 0 : tb + 1;                                                 \
  } while (0)

  M_ITER(0, ca, na);
  M_ITER(1, na, ca);
  M_ITER(2, ca, na);
  M_ITER(3, na, ca);
#undef M_ITER
  // final chunk c=4 (uses ca, buf cb), no further issues
  __builtin_amdgcn_sched_barrier(0);
  asm volatile("s_waitcnt vmcnt(9)" ::: "memory");
  __builtin_amdgcn_s_barrier();
  __builtin_amdgcn_sched_barrier(0);
  {
    const ushort* wb = &B3[cb][0];
#pragma unroll
    for (int ct = 0; ct < 5; ++ct) {
      const int ob = (ctg0 + ct) * 512 + lswz;
      const short8 bh = *(const short8*)&wb[ob];
      const short8 bl = *(const short8*)&wb[ob + 5120];
#pragma unroll
      for (int rt = 0; rt < 4; ++rt) {
        acc[rt][ct] = mfma16(ca[rt], bh, acc[rt][ct]);
        acc[rt][ct] = mfma16(ca[rt], bl, acc[rt][ct]);
      }
    }
  }

  // layer 3 + cross-column-wave reduction
  __syncthreads();
  float* Pr = (float*)&B3[0][0];   // [2][ROWS2]
#pragma unroll
  for (int rt = 0; rt < 4; ++rt)
#pragma unroll
    for (int q = 0; q < 4; ++q) {
      float s = 0.f;
#pragma unroll
      for (int ct = 0; ct < 5; ++ct)
        s = fmaf(fmaxf(acc[rt][ct][q] + b2v[ct], 0.f), w3v[ct], s);
      s += __shfl_xor(s, 1); s += __shfl_xor(s, 2);
      s += __shfl_xor(s, 4); s += __shfl_xor(s, 8);
      if (l15 == 0) Pr[cw * ROWS2 + rw * 64 + rt * 16 + kb * 4 + q] = s;
    }
  __syncthreads();
  if (tid < ROWS2) {
    const int gr = r0 + tid;
    if (gr < NP) out[gr] = Pr[tid] + Pr[ROWS2 + tid] + b3v;
  }
}

extern "C" void kernel_launch(void* const* d_in, const int* in_sizes, int n_in,
                              void* d_out, int out_size, void* d_ws, size_t ws_size,
                              hipStream_t stream) {
  const float* M    = (const float*)d_in[0];
  const int*   pidx = (const int*)d_in[1];
  const float* W1   = (const float*)d_in[3];
  const float* b1   = (const float*)d_in[4];
  const float* W2   = (const float*)d_in[5];
  const float* b2   = (const float*)d_in[6];
  const float* W3   = (const float*)d_in[7];
  const float* b3   = (const float*)d_in[8];
  float* out = (float*)d_out;

  const int P = in_sizes[1];
  const int NP = out_size;
  int K = 50;
  for (int k = 1; k <= P; ++k) {
    const long long np = (long long)k * (k - 1) / 2 + (long long)(P - k) * k;
    if (np == (long long)NP) { K = k; break; }
  }
  const int nb1 = (NP + ROWS1 - 1) / ROWS1;
  const int nb2 = (NP + ROWS2 - 1) / ROWS2;
  const size_t h1rows = (size_t)max(nb1 * ROWS1, nb2 * ROWS2);

  // ws: G [P][1216] f32 | AB [2][P][160] f32 | W1ch 3*38*10240 us | W2ch 5*10240 us | H1 [h1rows][160] us
  float* G = (float*)d_ws;
  float* AB = G + (size_t)P * DP;
  ushort* W1ch = (ushort*)(AB + (size_t)2 * P * HPAD);
  ushort* W2ch = W1ch + (size_t)3 * NKC * WCHU;
  ushort* H1 = W2ch + (size_t)NKC2 * WCHU;
  (void)h1rows;

  const int prepN = 3 * NKC * HPAD * 32 + NKC2 * HPAD * 32;
  k_prep<<<(prepN + 255) / 256, 256, 0, stream>>>(W1, W2, W1ch, W2ch);
  k_gather<<<P, 256, 0, stream>>>(M, pidx, G);
  dim3 gp((P + RPC - 1) / RPC, 2);
  k_precomp<<<gp, 256, 0, stream>>>(G, W1ch, b1, AB, P);
  k_pair_l1<<<nb1, 256, 0, stream>>>(G, W1ch, AB, H1, P, K, NP);
  k_mlp<<<nb2, 256, 0, stream>>>(H1, W2ch, b2, W3, b3, out, NP);
}

// Round 5
// 239.627 us; speedup vs baseline: 1.4161x; 1.4161x over previous
//
#include <hip/hip_runtime.h>

// PairwiseScore round 5: revert to round-3 2-phase structure; 2-term split
// (X hi/lo x W bf16-hi) for the pair GEMM -> -33% MFMA, -50% W LDS/DMA,
// 3 blocks/CU.  A/B mention terms stay 3-term (hi/lo W) for accuracy.
//   h1 = relu(gi@W1a + gj@W1b + (gi.gj)@W1c + b1)
//   out = relu(h1@W2 + b2) @ W3 + b3
// Shapes: M=10000, D=1200(->1216), P=2000, K=50, H=150(->160), NP=98725.

typedef __attribute__((ext_vector_type(8))) short short8;
typedef __attribute__((ext_vector_type(4))) float f32x4;

constexpr int DP    = 1216;      // padded G_DIM (38*32)
constexpr int HPAD  = 160;       // padded hidden
constexpr int NKC   = 38;        // K-chunks of 32 over DP
constexpr int NKC2  = 5;         // K-chunks of 32 over HPAD
constexpr int WCHU  = 10240;     // ushorts per hi+lo W chunk image (A/B precomp)
constexpr int WCH1  = 5120;      // ushorts per hi-only W chunk image
constexpr int ROWS  = 128;       // rows per block (4 waves x 2 tiles x 16)

__device__ __forceinline__ ushort bf16_rne(float x) {
  uint u = __float_as_uint(x);
  u += 0x7FFFu + ((u >> 16) & 1u);
  return (ushort)(u >> 16);
}
__device__ __forceinline__ float bf16f(ushort h) {
  return __uint_as_float((uint)h << 16);
}
__device__ __forceinline__ f32x4 mfma16(short8 a, short8 b, f32x4 c) {
  return __builtin_amdgcn_mfma_f32_16x16x32_bf16(a, b, c, 0, 0, 0);
}
__device__ __forceinline__ void g2lds16(const void* g, void* l) {
  __builtin_amdgcn_global_load_lds(
      (const __attribute__((address_space(1))) void*)g,
      (__attribute__((address_space(3))) void*)l, 16, 0, 0);
}
// stage a 10240B hi-only chunk: rounds 0,1 all 4 waves, round 2 waves 0,1
__device__ __forceinline__ void stage_hi(const ushort* gs, ushort* lb,
                                         int w, int lane) {
  const char* g = (const char*)gs + w * 1024 + lane * 16;
  char* l = (char*)lb + w * 1024;
  g2lds16(g, l);
  g2lds16(g + 4096, l + 4096);
  if (w < 2) g2lds16(g + 8192, l + 8192);
}
// stage a 20480B hi+lo chunk (A/B precomp path)
__device__ __forceinline__ void stage_chunk(const ushort* gsrc, ushort* lbuf,
                                            int w, int lane) {
  const char* g = (const char*)gsrc + w * 5120 + lane * 16;
  char* l = (char*)lbuf + w * 5120;
#pragma unroll
  for (int q = 0; q < 5; ++q) g2lds16(g + q * 1024, l + q * 1024);
}
// split product gi*gj (8 elems) into bf16 hi (trunc) + lo (trunc residual)
__device__ __forceinline__ void split8(const float* a, const float* b,
                                       short8& hi, short8& lo) {
  const float4 a0 = *(const float4*)a, a1 = *(const float4*)(a + 4);
  const float4 b0 = *(const float4*)b, b1 = *(const float4*)(b + 4);
  float p[8] = {a0.x * b0.x, a0.y * b0.y, a0.z * b0.z, a0.w * b0.w,
                a1.x * b1.x, a1.y * b1.y, a1.z * b1.z, a1.w * b1.w};
  uint h[4], l[4];
#pragma unroll
  for (int e = 0; e < 4; ++e) {
    uint u0 = __float_as_uint(p[2 * e]), u1 = __float_as_uint(p[2 * e + 1]);
    float r0 = p[2 * e] - __uint_as_float(u0 & 0xffff0000u);
    float r1 = p[2 * e + 1] - __uint_as_float(u1 & 0xffff0000u);
    h[e] = __builtin_amdgcn_perm(u1, u0, 0x07060302u);
    l[e] = __builtin_amdgcn_perm(__float_as_uint(r1), __float_as_uint(r0),
                                 0x07060302u);
  }
  uint4 hu = make_uint4(h[0], h[1], h[2], h[3]);
  uint4 lu = make_uint4(l[0], l[1], l[2], l[3]);
  hi = *(short8*)&hu; lo = *(short8*)&lu;
}
__device__ __forceinline__ void split1(const float* a, short8& hi, short8& lo) {
  const float4 a0 = *(const float4*)a, a1 = *(const float4*)(a + 4);
  float p[8] = {a0.x, a0.y, a0.z, a0.w, a1.x, a1.y, a1.z, a1.w};
  uint h[4], l[4];
#pragma unroll
  for (int e = 0; e < 4; ++e) {
    uint u0 = __float_as_uint(p[2 * e]), u1 = __float_as_uint(p[2 * e + 1]);
    float r0 = p[2 * e] - __uint_as_float(u0 & 0xffff0000u);
    float r1 = p[2 * e + 1] - __uint_as_float(u1 & 0xffff0000u);
    h[e] = __builtin_amdgcn_perm(u1, u0, 0x07060302u);
    l[e] = __builtin_amdgcn_perm(__float_as_uint(r1), __float_as_uint(r0),
                                 0x07060302u);
  }
  uint4 hu = make_uint4(h[0], h[1], h[2], h[3]);
  uint4 lu = make_uint4(l[0], l[1], l[2], l[3]);
  hi = *(short8*)&hu; lo = *(short8*)&lu;
}
__device__ __forceinline__ void pair_ij(int r, int K, int NP, int& i, int& j) {
  if (r >= NP) { i = 1; j = 0; return; }
  const int T = K * (K - 1) / 2;
  if (r < T) {
    int ii = (int)((1.0f + sqrtf(1.0f + 8.0f * (float)r)) * 0.5f);
    while (ii * (ii - 1) / 2 > r) --ii;
    while ((ii + 1) * ii / 2 <= r) ++ii;
    i = ii; j = r - ii * (ii - 1) / 2;
  } else {
    const int rp = r - T, q = rp / K;
    i = K + q; j = i - K + (rp - q * K);
  }
}

// ---------- k_prep ----------
// W1ab: [2 slabs][38][hi 5120 | lo 5120]  (for k_precomp, 3-term)
// W1c_hi: [38][5120], W2_hi: [5][5120]    (hi only, swizzled)
__global__ void k_prep(const float* __restrict__ W1, const float* __restrict__ W2,
                       ushort* __restrict__ W1ab, ushort* __restrict__ W1c_hi,
                       ushort* __restrict__ W2_hi) {
  const int NAB = 2 * NKC * HPAD * 32;
  const int NC = NKC * HPAD * 32;
  int idx = blockIdx.x * 256 + threadIdx.x;
  if (idx < NAB) {
    int s = idx / NC, r1 = idx % NC;
    int c = r1 / (HPAD * 32), r2 = r1 % (HPAD * 32);
    int col = r2 >> 5, kk = r2 & 31;
    int k = c * 32 + kk;
    float v = (k < 1200 && col < 150) ? W1[((size_t)s * 1200 + k) * 150 + col] : 0.f;
    ushort h = bf16_rne(v);
    ushort l = bf16_rne(v - bf16f(h));
    size_t base = (size_t)(s * NKC + c) * WCHU;
    int i0 = (col * 32 + kk) ^ ((col & 7) << 3);
    W1ab[base + i0] = h;
    W1ab[base + i0 + 5120] = l;
  } else if (idx < NAB + NC) {
    int r1 = idx - NAB;
    int c = r1 / (HPAD * 32), r2 = r1 % (HPAD * 32);
    int col = r2 >> 5, kk = r2 & 31;
    int k = c * 32 + kk;
    float v = (k < 1200 && col < 150)
                  ? W1[((size_t)2 * 1200 + k) * 150 + col] : 0.f;
    int i0 = (col * 32 + kk) ^ ((col & 7) << 3);
    W1c_hi[(size_t)c * WCH1 + i0] = bf16_rne(v);
  } else {
    int r1 = idx - NAB - NC;
    if (r1 < NKC2 * HPAD * 32) {
      int c = r1 / (HPAD * 32), r2 = r1 % (HPAD * 32);
      int col = r2 >> 5, kk = r2 & 31;
      int k = c * 32 + kk;
      float v = (k < 150 && col < 150) ? W2[(size_t)k * 150 + col] : 0.f;
      int i0 = (col * 32 + kk) ^ ((col & 7) << 3);
      W2_hi[(size_t)c * WCH1 + i0] = bf16_rne(v);
    }
  }
}

// ---------- k_gather ----------
__global__ void k_gather(const float* __restrict__ M, const int* __restrict__ pidx,
                         float* __restrict__ G) {
  const int i = blockIdx.x;
  const int r = pidx[i];
  const float4* src = reinterpret_cast<const float4*>(M + (size_t)r * 1200);
  float4* dst = reinterpret_cast<float4*>(G + (size_t)i * DP);
  for (int t = threadIdx.x; t < DP / 4; t += blockDim.x)
    dst[t] = (t < 300) ? src[t] : make_float4(0.f, 0.f, 0.f, 0.f);
}

// ---------- k_precomp: AB[slab][r][col] = G[r]@W1slab (+b1 if slab0), 3-term ----------
__global__ __launch_bounds__(256, 3) void k_precomp(
    const float* __restrict__ G, const ushort* __restrict__ W1ab,
    const float* __restrict__ b1, float* __restrict__ AB, int P) {
  __shared__ __align__(16) ushort Wb0[WCHU];
  __shared__ __align__(16) ushort Wb1[WCHU];
  const int tid = threadIdx.x, lane = tid & 63, w = tid >> 6;
  const int l15 = lane & 15, kb = lane >> 4;
  const int r0 = blockIdx.x * ROWS;
  const int slab = blockIdx.y;
  const ushort* wsrc = W1ab + (size_t)slab * NKC * WCHU;

  const int row0 = min(r0 + w * 32 + l15, P - 1);
  const int row1 = min(r0 + w * 32 + 16 + l15, P - 1);
  const float* g0 = G + (size_t)row0 * DP + kb * 8;
  const float* g1 = G + (size_t)row1 * DP + kb * 8;
  const int lbase = (l15 * 32 + kb * 8) ^ ((l15 & 7) << 3);

  f32x4 acc[2][10];
#pragma unroll
  for (int a = 0; a < 2; ++a)
#pragma unroll
    for (int b = 0; b < 10; ++b) acc[a][b] = (f32x4)(0.f);

  stage_chunk(wsrc, Wb0, w, lane);
  short8 ah0, al0, ah1, al1;
  split1(g0, ah0, al0);
  split1(g1, ah1, al1);

#pragma unroll 2
  for (int c = 0; c < NKC; ++c) {
    __syncthreads();
    if (c < NKC - 1)
      stage_chunk(wsrc + (size_t)(c + 1) * WCHU, (c & 1) ? Wb0 : Wb1, w, lane);
    const ushort* wb = (c & 1) ? Wb1 : Wb0;
#pragma unroll
    for (int ct = 0; ct < 10; ++ct) {
      const short8 bh = *(const short8*)&wb[lbase + ct * 512];
      const short8 bl = *(const short8*)&wb[lbase + ct * 512 + 5120];
      acc[0][ct] = mfma16(ah0, bh, acc[0][ct]);
      acc[1][ct] = mfma16(ah1, bh, acc[1][ct]);
      acc[0][ct] = mfma16(al0, bh, acc[0][ct]);
      acc[1][ct] = mfma16(al1, bh, acc[1][ct]);
      acc[0][ct] = mfma16(ah0, bl, acc[0][ct]);
      acc[1][ct] = mfma16(ah1, bl, acc[1][ct]);
    }
    if (c < NKC - 1) {
      split1(g0 + (c + 1) * 32, ah0, al0);
      split1(g1 + (c + 1) * 32, ah1, al1);
    }
  }
  float* outp = AB + (size_t)slab * P * HPAD;
#pragma unroll
  for (int rt = 0; rt < 2; ++rt)
#pragma unroll
    for (int q = 0; q < 4; ++q) {
      const int r = r0 + w * 32 + rt * 16 + kb * 4 + q;
      if (r < P) {
#pragma unroll
        for (int ct = 0; ct < 10; ++ct) {
          const int col = ct * 16 + l15;
          float v = acc[rt][ct][q];
          if (slab == 0 && col < 150) v += b1[col];
          outp[(size_t)r * HPAD + col] = v;
        }
      }
    }
}

// ---------- k_pair_l1: bilinear pair GEMM -> H1 bf16 (2-term, hi-only W) ----------
__global__ __launch_bounds__(256, 3) void k_pair_l1(
    const float* __restrict__ G, const ushort* __restrict__ W1c_hi,
    const float* __restrict__ AB, ushort* __restrict__ H1,
    int P, int K, int NP) {
  __shared__ __align__(16) ushort Wb[2][WCH1];   // 20 KB
  __shared__ int tI[ROWS], tJ[ROWS];
  const int tid = threadIdx.x, lane = tid & 63, w = tid >> 6;
  const int l15 = lane & 15, kb = lane >> 4;
  const int r0 = blockIdx.x * ROWS;

  if (tid < ROWS) {
    int i, j;
    pair_ij(r0 + tid, K, NP, i, j);
    tI[tid] = i; tJ[tid] = j;
  }
  stage_hi(W1c_hi, Wb[0], w, lane);
  __syncthreads();

  const int rowA = w * 32 + l15, rowB = rowA + 16;
  const float* gi0 = G + (size_t)tI[rowA] * DP + kb * 8;
  const float* gj0 = G + (size_t)tJ[rowA] * DP + kb * 8;
  const float* gi1 = G + (size_t)tI[rowB] * DP + kb * 8;
  const float* gj1 = G + (size_t)tJ[rowB] * DP + kb * 8;
  const int lswz = (l15 * 32 + kb * 8) ^ ((l15 & 7) << 3);

  f32x4 acc[2][10];
#pragma unroll
  for (int a = 0; a < 2; ++a)
#pragma unroll
    for (int b = 0; b < 10; ++b) acc[a][b] = (f32x4)(0.f);

  short8 ah0, al0, ah1, al1;
  split8(gi0, gj0, ah0, al0);
  split8(gi1, gj1, ah1, al1);

#pragma unroll 2
  for (int c = 0; c < NKC; ++c) {
    if (c) __syncthreads();
    if (c < NKC - 1)
      stage_hi(W1c_hi + (size_t)(c + 1) * WCH1, Wb[(c + 1) & 1], w, lane);
    const ushort* wb = Wb[c & 1];
#pragma unroll
    for (int ct = 0; ct < 10; ++ct) {
      const short8 bh = *(const short8*)&wb[ct * 512 + lswz];
      acc[0][ct] = mfma16(ah0, bh, acc[0][ct]);
      acc[1][ct] = mfma16(ah1, bh, acc[1][ct]);
      acc[0][ct] = mfma16(al0, bh, acc[0][ct]);
      acc[1][ct] = mfma16(al1, bh, acc[1][ct]);
    }
    if (c < NKC - 1) {
      split8(gi0 + (c + 1) * 32, gj0 + (c + 1) * 32, ah0, al0);
      split8(gi1 + (c + 1) * 32, gj1 + (c + 1) * 32, ah1, al1);
    }
  }

  // epilogue: h1 = relu(acc + A[i] + B[j]) -> H1 bf16
#pragma unroll
  for (int rt = 0; rt < 2; ++rt)
#pragma unroll
    for (int q = 0; q < 4; ++q) {
      const int rr = w * 32 + rt * 16 + kb * 4 + q;
      const float* Ar = AB + (size_t)tI[rr] * HPAD;
      const float* Br = AB + ((size_t)P + tJ[rr]) * HPAD;
      ushort* hrow = H1 + (size_t)(r0 + rr) * HPAD;
#pragma unroll
      for (int ct = 0; ct < 10; ++ct) {
        const int col = ct * 16 + l15;
        const float v = acc[rt][ct][q] + Ar[col] + Br[col];
        hrow[col] = bf16_rne(fmaxf(v, 0.f));
      }
    }
}

// ---------- k_mlp: out = relu(H1@W2 + b2) @ W3 + b3 (1-term, hi-only W2) ----------
__global__ __launch_bounds__(256, 3) void k_mlp(
    const ushort* __restrict__ H1, const ushort* __restrict__ W2_hi,
    const float* __restrict__ b2, const float* __restrict__ W3,
    const float* __restrict__ b3, float* __restrict__ out, int NP) {
  __shared__ __align__(16) ushort Wb[2][WCH1];
  const int tid = threadIdx.x, lane = tid & 63, w = tid >> 6;
  const int l15 = lane & 15, kb = lane >> 4;
  const int r0 = blockIdx.x * ROWS;
  const int lswz = (l15 * 32 + kb * 8) ^ ((l15 & 7) << 3);

  const ushort* h0 = H1 + (size_t)(r0 + w * 32 + l15) * HPAD + kb * 8;
  const ushort* h1 = H1 + (size_t)(r0 + w * 32 + 16 + l15) * HPAD + kb * 8;

  f32x4 acc[2][10];
#pragma unroll
  for (int a = 0; a < 2; ++a)
#pragma unroll
    for (int b = 0; b < 10; ++b) acc[a][b] = (f32x4)(0.f);

  stage_hi(W2_hi, Wb[0], w, lane);
  short8 a0 = *(const short8*)h0;
  short8 a1 = *(const short8*)h1;

#pragma unroll
  for (int c = 0; c < NKC2; ++c) {
    __syncthreads();
    if (c < NKC2 - 1)
      stage_hi(W2_hi + (size_t)(c + 1) * WCH1, Wb[(c + 1) & 1], w, lane);
    const ushort* wb = Wb[c & 1];
#pragma unroll
    for (int ct = 0; ct < 10; ++ct) {
      const short8 bh = *(const short8*)&wb[ct * 512 + lswz];
      acc[0][ct] = mfma16(a0, bh, acc[0][ct]);
      acc[1][ct] = mfma16(a1, bh, acc[1][ct]);
    }
    if (c < NKC2 - 1) {
      a0 = *(const short8*)(h0 + (c + 1) * 32);
      a1 = *(const short8*)(h1 + (c + 1) * 32);
    }
  }
  const float b3v = b3[0];
#pragma unroll
  for (int rt = 0; rt < 2; ++rt)
#pragma unroll
    for (int q = 0; q < 4; ++q) {
      float s = 0.f;
#pragma unroll
      for (int ct = 0; ct < 10; ++ct) {
        const int col = ct * 16 + l15;
        const float b2c = (col < 150) ? b2[col] : 0.f;
        const float w3c = (col < 150) ? W3[col] : 0.f;
        s = fmaf(fmaxf(acc[rt][ct][q] + b2c, 0.f), w3c, s);
      }
      s += __shfl_xor(s, 1); s += __shfl_xor(s, 2);
      s += __shfl_xor(s, 4); s += __shfl_xor(s, 8);
      if (l15 == 0) {
        const int gr = r0 + w * 32 + rt * 16 + kb * 4 + q;
        if (gr < NP) out[gr] = s + b3v;
      }
    }
}

extern "C" void kernel_launch(void* const* d_in, const int* in_sizes, int n_in,
                              void* d_out, int out_size, void* d_ws, size_t ws_size,
                              hipStream_t stream) {
  const float* M    = (const float*)d_in[0];
  const int*   pidx = (const int*)d_in[1];
  const float* W1   = (const float*)d_in[3];
  const float* b1   = (const float*)d_in[4];
  const float* W2   = (const float*)d_in[5];
  const float* b2   = (const float*)d_in[6];
  const float* W3   = (const float*)d_in[7];
  const float* b3   = (const float*)d_in[8];
  float* out = (float*)d_out;

  const int P = in_sizes[1];
  const int NP = out_size;
  int K = 50;
  for (int k = 1; k <= P; ++k) {
    const long long np = (long long)k * (k - 1) / 2 + (long long)(P - k) * k;
    if (np == (long long)NP) { K = k; break; }
  }
  const int nb = (NP + ROWS - 1) / ROWS;

  // ws: G [P][1216] f32 | AB [2][P][160] f32 | W1ab 2*38*10240 us |
  //     W1c_hi 38*5120 us | W2_hi 5*5120 us | H1 [nb*128][160] us
  float* G = (float*)d_ws;
  float* AB = G + (size_t)P * DP;
  ushort* W1ab = (ushort*)(AB + (size_t)2 * P * HPAD);
  ushort* W1c_hi = W1ab + (size_t)2 * NKC * WCHU;
  ushort* W2_hi = W1c_hi + (size_t)NKC * WCH1;
  ushort* H1 = W2_hi + (size_t)NKC2 * WCH1;

  const int prepN = 2 * NKC * HPAD * 32 + NKC * HPAD * 32 + NKC2 * HPAD * 32;
  k_prep<<<(prepN + 255) / 256, 256, 0, stream>>>(W1, W2, W1ab, W1c_hi, W2_hi);
  k_gather<<<P, 256, 0, stream>>>(M, pidx, G);
  dim3 gp((P + ROWS - 1) / ROWS, 2);
  k_precomp<<<gp, 256, 0, stream>>>(G, W1ab, b1, AB, P);
  k_pair_l1<<<nb, 256, 0, stream>>>(G, W1c_hi, AB, H1, P, K, NP);
  k_mlp<<<nb, 256, 0, stream>>>(H1, W2_hi, b2, W3, b3, out, NP);
}

// Round 6
// 223.606 us; speedup vs baseline: 1.5176x; 1.0716x over previous
//
#include <hip/hip_runtime.h>

// PairwiseScore round 6: dense pairs share a sliding K-window of mentions ->
// i-grouped blocks (TI=2 i's, 100 pairs) stage the contiguous 52-row G slice
// per K-chunk into LDS (global_load_lds, inverse-swizzled source), killing the
// per-pair global gather (920MB -> 247MB) and its latency. XCD swizzle for
// cross-block window reuse. Head/tail pairs use the generic gather kernel.
//   h1 = relu(gi@W1a + gj@W1b + (gi.gj)@W1c + b1)   [A/B precomp per mention]
//   out = relu(h1@W2 + b2) @ W3 + b3
// Shapes: M=10000, D=1200(->1216), P=2000, K=50, H=150(->160), NP=98725.

typedef __attribute__((ext_vector_type(8))) short short8;
typedef __attribute__((ext_vector_type(4))) float f32x4;

constexpr int DP    = 1216;      // padded G_DIM (38*32)
constexpr int HPAD  = 160;       // padded hidden
constexpr int NKC   = 38;        // K-chunks of 32 over DP
constexpr int NKC2  = 5;         // K-chunks of 32 over HPAD
constexpr int WCHU  = 10240;     // ushorts per hi+lo W chunk image (precomp)
constexpr int WCH1  = 5120;      // ushorts per hi-only W chunk image
constexpr int ROWS  = 128;       // rows per block (generic / mlp)
constexpr int KD    = 50;        // compile-time K for the dense kernel
constexpr int TI    = 2;         // i's per dense block
constexpr int PB    = TI * KD;   // 100 pairs per dense block
constexpr int NGR   = KD + TI;   // 52 staged G rows per dense block
constexpr int TD    = KD * (KD - 1) / 2;  // 1225 head pairs

__device__ __forceinline__ ushort bf16_rne(float x) {
  uint u = __float_as_uint(x);
  u += 0x7FFFu + ((u >> 16) & 1u);
  return (ushort)(u >> 16);
}
__device__ __forceinline__ float bf16f(ushort h) {
  return __uint_as_float((uint)h << 16);
}
__device__ __forceinline__ f32x4 mfma16(short8 a, short8 b, f32x4 c) {
  return __builtin_amdgcn_mfma_f32_16x16x32_bf16(a, b, c, 0, 0, 0);
}
__device__ __forceinline__ void g2lds16(const void* g, void* l) {
  __builtin_amdgcn_global_load_lds(
      (const __attribute__((address_space(1))) void*)g,
      (__attribute__((address_space(3))) void*)l, 16, 0, 0);
}
// stage a 10240B hi-only W chunk: rounds 0,1 all 4 waves, round 2 waves 0,1
__device__ __forceinline__ void stage_hi(const ushort* gs, ushort* lb,
                                         int w, int lane) {
  const char* g = (const char*)gs + w * 1024 + lane * 16;
  char* l = (char*)lb + w * 1024;
  g2lds16(g, l);
  g2lds16(g + 4096, l + 4096);
  if (w < 2) g2lds16(g + 8192, l + 8192);
}
// stage a 20480B hi+lo chunk (precomp path)
__device__ __forceinline__ void stage_chunk(const ushort* gsrc, ushort* lbuf,
                                            int w, int lane) {
  const char* g = (const char*)gsrc + w * 5120 + lane * 16;
  char* l = (char*)lbuf + w * 5120;
#pragma unroll
  for (int q = 0; q < 5; ++q) g2lds16(g + q * 1024, l + q * 1024);
}
// stage the 52-row x 32-col f32 G slice (chunk c) with inverse-XOR source so
// reads at slot row*8 + (grp ^ (row&7)) are bank-spread (rule #21).
__device__ __forceinline__ void stage_G(const float* __restrict__ G, int b0,
                                        int c, float* buf, int w, int lane) {
#pragma unroll
  for (int r = 0; r < 2; ++r) {
    const int slot = r * 256 + w * 64 + lane;
    int row = slot >> 3, grp = slot & 7;
    row = min(row, NGR - 1);
    const float* src =
        G + (size_t)(b0 + row) * DP + c * 32 + ((grp ^ (row & 7)) << 2);
    char* dst = (char*)buf + (r * 256 + w * 64) * 16;  // wave-uniform base
    g2lds16(src, dst);
  }
}
// split product a*b (8 elems) into bf16 hi (trunc) + lo (trunc residual)
__device__ __forceinline__ void splitp(float4 a0, float4 a1, float4 b0,
                                       float4 b1, short8& hi, short8& lo) {
  float p[8] = {a0.x * b0.x, a0.y * b0.y, a0.z * b0.z, a0.w * b0.w,
                a1.x * b1.x, a1.y * b1.y, a1.z * b1.z, a1.w * b1.w};
  uint h[4], l[4];
#pragma unroll
  for (int e = 0; e < 4; ++e) {
    uint u0 = __float_as_uint(p[2 * e]), u1 = __float_as_uint(p[2 * e + 1]);
    float r0 = p[2 * e] - __uint_as_float(u0 & 0xffff0000u);
    float r1 = p[2 * e + 1] - __uint_as_float(u1 & 0xffff0000u);
    h[e] = __builtin_amdgcn_perm(u1, u0, 0x07060302u);
    l[e] = __builtin_amdgcn_perm(__float_as_uint(r1), __float_as_uint(r0),
                                 0x07060302u);
  }
  uint4 hu = make_uint4(h[0], h[1], h[2], h[3]);
  uint4 lu = make_uint4(l[0], l[1], l[2], l[3]);
  hi = *(short8*)&hu; lo = *(short8*)&lu;
}
__device__ __forceinline__ void split1(const float* a, short8& hi, short8& lo) {
  const float4 a0 = *(const float4*)a, a1 = *(const float4*)(a + 4);
  float p[8] = {a0.x, a0.y, a0.z, a0.w, a1.x, a1.y, a1.z, a1.w};
  uint h[4], l[4];
#pragma unroll
  for (int e = 0; e < 4; ++e) {
    uint u0 = __float_as_uint(p[2 * e]), u1 = __float_as_uint(p[2 * e + 1]);
    float r0 = p[2 * e] - __uint_as_float(u0 & 0xffff0000u);
    float r1 = p[2 * e + 1] - __uint_as_float(u1 & 0xffff0000u);
    h[e] = __builtin_amdgcn_perm(u1, u0, 0x07060302u);
    l[e] = __builtin_amdgcn_perm(__float_as_uint(r1), __float_as_uint(r0),
                                 0x07060302u);
  }
  uint4 hu = make_uint4(h[0], h[1], h[2], h[3]);
  uint4 lu = make_uint4(l[0], l[1], l[2], l[3]);
  hi = *(short8*)&hu; lo = *(short8*)&lu;
}
__device__ __forceinline__ void pair_ij(int r, int K, int NP, int& i, int& j) {
  if (r >= NP) { i = 1; j = 0; return; }
  const int T = K * (K - 1) / 2;
  if (r < T) {
    int ii = (int)((1.0f + sqrtf(1.0f + 8.0f * (float)r)) * 0.5f);
    while (ii * (ii - 1) / 2 > r) --ii;
    while ((ii + 1) * ii / 2 <= r) ++ii;
    i = ii; j = r - ii * (ii - 1) / 2;
  } else {
    const int rp = r - T, q = rp / K;
    i = K + q; j = i - K + (rp - q * K);
  }
}

// ---------- k_prep ----------
__global__ void k_prep(const float* __restrict__ W1, const float* __restrict__ W2,
                       ushort* __restrict__ W1ab, ushort* __restrict__ W1c_hi,
                       ushort* __restrict__ W2_hi) {
  const int NAB = 2 * NKC * HPAD * 32;
  const int NC = NKC * HPAD * 32;
  int idx = blockIdx.x * 256 + threadIdx.x;
  if (idx < NAB) {
    int s = idx / NC, r1 = idx % NC;
    int c = r1 / (HPAD * 32), r2 = r1 % (HPAD * 32);
    int col = r2 >> 5, kk = r2 & 31;
    int k = c * 32 + kk;
    float v = (k < 1200 && col < 150) ? W1[((size_t)s * 1200 + k) * 150 + col] : 0.f;
    ushort h = bf16_rne(v);
    ushort l = bf16_rne(v - bf16f(h));
    size_t base = (size_t)(s * NKC + c) * WCHU;
    int i0 = (col * 32 + kk) ^ ((col & 7) << 3);
    W1ab[base + i0] = h;
    W1ab[base + i0 + 5120] = l;
  } else if (idx < NAB + NC) {
    int r1 = idx - NAB;
    int c = r1 / (HPAD * 32), r2 = r1 % (HPAD * 32);
    int col = r2 >> 5, kk = r2 & 31;
    int k = c * 32 + kk;
    float v = (k < 1200 && col < 150)
                  ? W1[((size_t)2 * 1200 + k) * 150 + col] : 0.f;
    int i0 = (col * 32 + kk) ^ ((col & 7) << 3);
    W1c_hi[(size_t)c * WCH1 + i0] = bf16_rne(v);
  } else {
    int r1 = idx - NAB - NC;
    if (r1 < NKC2 * HPAD * 32) {
      int c = r1 / (HPAD * 32), r2 = r1 % (HPAD * 32);
      int col = r2 >> 5, kk = r2 & 31;
      int k = c * 32 + kk;
      float v = (k < 150 && col < 150) ? W2[(size_t)k * 150 + col] : 0.f;
      int i0 = (col * 32 + kk) ^ ((col & 7) << 3);
      W2_hi[(size_t)c * WCH1 + i0] = bf16_rne(v);
    }
  }
}

// ---------- k_gather ----------
__global__ void k_gather(const float* __restrict__ M, const int* __restrict__ pidx,
                         float* __restrict__ G) {
  const int i = blockIdx.x;
  const int r = pidx[i];
  const float4* src = reinterpret_cast<const float4*>(M + (size_t)r * 1200);
  float4* dst = reinterpret_cast<float4*>(G + (size_t)i * DP);
  for (int t = threadIdx.x; t < DP / 4; t += blockDim.x)
    dst[t] = (t < 300) ? src[t] : make_float4(0.f, 0.f, 0.f, 0.f);
}

// ---------- k_precomp: 32 rows/block, 4 waves = 2 row-tiles x 2 col-halves ----------
__global__ __launch_bounds__(256, 4) void k_precomp(
    const float* __restrict__ G, const ushort* __restrict__ W1ab,
    const float* __restrict__ b1, float* __restrict__ AB, int P) {
  __shared__ __align__(16) ushort Wb[2][WCHU];
  const int tid = threadIdx.x, lane = tid & 63, w = tid >> 6;
  const int l15 = lane & 15, kb = lane >> 4;
  const int rt = w & 1, ch = w >> 1;
  const int r0 = blockIdx.x * 32;
  const int slab = blockIdx.y;
  const ushort* wsrc = W1ab + (size_t)slab * NKC * WCHU;

  const int row = min(r0 + rt * 16 + l15, P - 1);
  const float* g = G + (size_t)row * DP + kb * 8;
  const int lbase = (l15 * 32 + kb * 8) ^ ((l15 & 7) << 3);

  f32x4 acc[5];
#pragma unroll
  for (int b = 0; b < 5; ++b) acc[b] = (f32x4)(0.f);

  stage_chunk(wsrc, Wb[0], w, lane);
  short8 ah, al;
  split1(g, ah, al);

  for (int c = 0; c < NKC; ++c) {
    __syncthreads();
    if (c < NKC - 1)
      stage_chunk(wsrc + (size_t)(c + 1) * WCHU, Wb[(c + 1) & 1], w, lane);
    const ushort* wb = Wb[c & 1];
#pragma unroll
    for (int ct = 0; ct < 5; ++ct) {
      const int ob = (ch * 5 + ct) * 512 + lbase;
      const short8 bh = *(const short8*)&wb[ob];
      const short8 bl = *(const short8*)&wb[ob + 5120];
      acc[ct] = mfma16(ah, bh, acc[ct]);
      acc[ct] = mfma16(al, bh, acc[ct]);
      acc[ct] = mfma16(ah, bl, acc[ct]);
    }
    if (c < NKC - 1) split1(g + (c + 1) * 32, ah, al);
  }
  float* outp = AB + (size_t)slab * P * HPAD;
#pragma unroll
  for (int q = 0; q < 4; ++q) {
    const int r = r0 + rt * 16 + kb * 4 + q;
    if (r < P) {
#pragma unroll
      for (int ct = 0; ct < 5; ++ct) {
        const int col = (ch * 5 + ct) * 16 + l15;
        float v = acc[ct][q];
        if (slab == 0 && col < 150) v += b1[col];
        outp[(size_t)r * HPAD + col] = v;
      }
    }
  }
}

// ---------- k_pair_gen: generic (gathered) pair GEMM, for head/tail/fallback ----------
__global__ __launch_bounds__(256, 3) void k_pair_gen(
    const float* __restrict__ G, const ushort* __restrict__ W1c_hi,
    const float* __restrict__ AB, ushort* __restrict__ H1,
    int P, int K, int NP, int r_base) {
  __shared__ __align__(16) ushort Wb[2][WCH1];
  __shared__ int tI[ROWS], tJ[ROWS];
  const int tid = threadIdx.x, lane = tid & 63, w = tid >> 6;
  const int l15 = lane & 15, kb = lane >> 4;
  const int r0 = r_base + blockIdx.x * ROWS;

  if (tid < ROWS) {
    int i, j;
    pair_ij(r0 + tid, K, NP, i, j);
    tI[tid] = i; tJ[tid] = j;
  }
  stage_hi(W1c_hi, Wb[0], w, lane);
  __syncthreads();

  const int rowA = w * 32 + l15, rowB = rowA + 16;
  const float* gi0 = G + (size_t)tI[rowA] * DP + kb * 8;
  const float* gj0 = G + (size_t)tJ[rowA] * DP + kb * 8;
  const float* gi1 = G + (size_t)tI[rowB] * DP + kb * 8;
  const float* gj1 = G + (size_t)tJ[rowB] * DP + kb * 8;
  const int lswz = (l15 * 32 + kb * 8) ^ ((l15 & 7) << 3);

  f32x4 acc[2][10];
#pragma unroll
  for (int a = 0; a < 2; ++a)
#pragma unroll
    for (int b = 0; b < 10; ++b) acc[a][b] = (f32x4)(0.f);

  short8 ah0, al0, ah1, al1;
  {
    float4 x0 = *(const float4*)gi0, x1 = *(const float4*)(gi0 + 4);
    float4 y0 = *(const float4*)gj0, y1 = *(const float4*)(gj0 + 4);
    splitp(x0, x1, y0, y1, ah0, al0);
    x0 = *(const float4*)gi1; x1 = *(const float4*)(gi1 + 4);
    y0 = *(const float4*)gj1; y1 = *(const float4*)(gj1 + 4);
    splitp(x0, x1, y0, y1, ah1, al1);
  }

#pragma unroll 2
  for (int c = 0; c < NKC; ++c) {
    if (c) __syncthreads();
    if (c < NKC - 1)
      stage_hi(W1c_hi + (size_t)(c + 1) * WCH1, Wb[(c + 1) & 1], w, lane);
    const ushort* wb = Wb[c & 1];
#pragma unroll
    for (int ct = 0; ct < 10; ++ct) {
      const short8 bh = *(const short8*)&wb[ct * 512 + lswz];
      acc[0][ct] = mfma16(ah0, bh, acc[0][ct]);
      acc[1][ct] = mfma16(ah1, bh, acc[1][ct]);
      acc[0][ct] = mfma16(al0, bh, acc[0][ct]);
      acc[1][ct] = mfma16(al1, bh, acc[1][ct]);
    }
    if (c < NKC - 1) {
      const int cn = c + 1;
      float4 x0 = *(const float4*)(gi0 + cn * 32), x1 = *(const float4*)(gi0 + cn * 32 + 4);
      float4 y0 = *(const float4*)(gj0 + cn * 32), y1 = *(const float4*)(gj0 + cn * 32 + 4);
      splitp(x0, x1, y0, y1, ah0, al0);
      x0 = *(const float4*)(gi1 + cn * 32); x1 = *(const float4*)(gi1 + cn * 32 + 4);
      y0 = *(const float4*)(gj1 + cn * 32); y1 = *(const float4*)(gj1 + cn * 32 + 4);
      splitp(x0, x1, y0, y1, ah1, al1);
    }
  }

#pragma unroll
  for (int rt = 0; rt < 2; ++rt)
#pragma unroll
    for (int q = 0; q < 4; ++q) {
      const int rr = w * 32 + rt * 16 + kb * 4 + q;
      const float* Ar = AB + (size_t)tI[rr] * HPAD;
      const float* Br = AB + ((size_t)P + tJ[rr]) * HPAD;
      ushort* hrow = H1 + (size_t)(r0 + rr) * HPAD;
#pragma unroll
      for (int ct = 0; ct < 10; ++ct) {
        const int col = ct * 16 + l15;
        const float v = acc[rt][ct][q] + Ar[col] + Br[col];
        hrow[col] = bf16_rne(fmaxf(v, 0.f));
      }
    }
}

// ---------- k_pair_dense: TI=2 i's/block, LDS-staged sliding G window ----------
__global__ __launch_bounds__(256, 3) void k_pair_dense(
    const float* __restrict__ G, const ushort* __restrict__ W1c_hi,
    const float* __restrict__ AB, ushort* __restrict__ H1, int P, int ND) {
  __shared__ __align__(16) ushort Wb[2][WCH1];   // 20480 B
  __shared__ __align__(16) float Gs[2][2048];    // 16384 B (512 slots x 16B x 2)
  const int tid = threadIdx.x, lane = tid & 63, w = tid >> 6;
  const int l15 = lane & 15, kb = lane >> 4;

  // bijective XCD swizzle: consecutive logical blocks colocate on one XCD
  const int q8 = ND >> 3, r8 = ND & 7;
  const int xcd = blockIdx.x & 7, sidx = blockIdx.x >> 3;
  const int bid = (xcd < r8) ? xcd * (q8 + 1) + sidx
                             : r8 * (q8 + 1) + (xcd - r8) * q8 + sidx;
  const int i0 = KD + bid * TI;
  const int b0 = i0 - KD;  // first staged G row

  // per-lane row slots (constant over chunks)
  int sgi0[2], sgi1[2], sgj0[2], sgj1[2];
#pragma unroll
  for (int rt = 0; rt < 2; ++rt) {
    const int rr = w * 32 + rt * 16 + l15;
    const int q = min(rr, PB - 1);
    const int li = KD + q / KD;
    const int lj = q / KD + q % KD;
    sgi0[rt] = li * 8 + ((2 * kb) ^ (li & 7));
    sgi1[rt] = li * 8 + ((2 * kb + 1) ^ (li & 7));
    sgj0[rt] = lj * 8 + ((2 * kb) ^ (lj & 7));
    sgj1[rt] = lj * 8 + ((2 * kb + 1) ^ (lj & 7));
  }
  const int lswz = (l15 * 32 + kb * 8) ^ ((l15 & 7) << 3);

  f32x4 acc[2][10];
#pragma unroll
  for (int a = 0; a < 2; ++a)
#pragma unroll
    for (int b = 0; b < 10; ++b) acc[a][b] = (f32x4)(0.f);

  stage_G(G, b0, 0, Gs[0], w, lane);
  stage_hi(W1c_hi, Wb[0], w, lane);
  __syncthreads();

#pragma unroll 2
  for (int c = 0; c < NKC; ++c) {
    if (c) __syncthreads();
    if (c < NKC - 1) {
      stage_G(G, b0, c + 1, Gs[(c + 1) & 1], w, lane);
      stage_hi(W1c_hi + (size_t)(c + 1) * WCH1, Wb[(c + 1) & 1], w, lane);
    }
    const float4* gp = (const float4*)Gs[c & 1];
    const ushort* wb = Wb[c & 1];
    short8 ah[2], al[2];
#pragma unroll
    for (int rt = 0; rt < 2; ++rt) {
      const float4 x0 = gp[sgi0[rt]], x1 = gp[sgi1[rt]];
      const float4 y0 = gp[sgj0[rt]], y1 = gp[sgj1[rt]];
      splitp(x0, x1, y0, y1, ah[rt], al[rt]);
    }
#pragma unroll
    for (int ct = 0; ct < 10; ++ct) {
      const short8 bh = *(const short8*)&wb[ct * 512 + lswz];
      acc[0][ct] = mfma16(ah[0], bh, acc[0][ct]);
      acc[1][ct] = mfma16(ah[1], bh, acc[1][ct]);
      acc[0][ct] = mfma16(al[0], bh, acc[0][ct]);
      acc[1][ct] = mfma16(al[1], bh, acc[1][ct]);
    }
  }

  // epilogue: h1 = relu(acc + A[i] + B[j]) -> H1 rows TD + bid*PB + q
#pragma unroll
  for (int rt = 0; rt < 2; ++rt)
#pragma unroll
    for (int qq = 0; qq < 4; ++qq) {
      const int rr = w * 32 + rt * 16 + kb * 4 + qq;
      if (rr < PB) {
        const int ii = i0 + rr / KD;
        const int jj = ii - KD + rr % KD;
        const float* Ar = AB + (size_t)ii * HPAD;
        const float* Br = AB + ((size_t)P + jj) * HPAD;
        ushort* hrow = H1 + (size_t)(TD + bid * PB + rr) * HPAD;
#pragma unroll
        for (int ct = 0; ct < 10; ++ct) {
          const int col = ct * 16 + l15;
          const float v = acc[rt][ct][qq] + Ar[col] + Br[col];
          hrow[col] = bf16_rne(fmaxf(v, 0.f));
        }
      }
    }
}

// ---------- k_mlp: out = relu(H1@W2 + b2) @ W3 + b3 (hi-only W2) ----------
__global__ __launch_bounds__(256, 3) void k_mlp(
    const ushort* __restrict__ H1, const ushort* __restrict__ W2_hi,
    const float* __restrict__ b2, const float* __restrict__ W3,
    const float* __restrict__ b3, float* __restrict__ out, int NP) {
  __shared__ __align__(16) ushort Wb[2][WCH1];
  const int tid = threadIdx.x, lane = tid & 63, w = tid >> 6;
  const int l15 = lane & 15, kb = lane >> 4;
  const int r0 = blockIdx.x * ROWS;
  const int lswz = (l15 * 32 + kb * 8) ^ ((l15 & 7) << 3);

  const ushort* h0 = H1 + (size_t)(r0 + w * 32 + l15) * HPAD + kb * 8;
  const ushort* h1 = H1 + (size_t)(r0 + w * 32 + 16 + l15) * HPAD + kb * 8;

  f32x4 acc[2][10];
#pragma unroll
  for (int a = 0; a < 2; ++a)
#pragma unroll
    for (int b = 0; b < 10; ++b) acc[a][b] = (f32x4)(0.f);

  stage_hi(W2_hi, Wb[0], w, lane);
  short8 a0 = *(const short8*)h0;
  short8 a1 = *(const short8*)h1;

#pragma unroll
  for (int c = 0; c < NKC2; ++c) {
    __syncthreads();
    if (c < NKC2 - 1)
      stage_hi(W2_hi + (size_t)(c + 1) * WCH1, Wb[(c + 1) & 1], w, lane);
    const ushort* wb = Wb[c & 1];
#pragma unroll
    for (int ct = 0; ct < 10; ++ct) {
      const short8 bh = *(const short8*)&wb[ct * 512 + lswz];
      acc[0][ct] = mfma16(a0, bh, acc[0][ct]);
      acc[1][ct] = mfma16(a1, bh, acc[1][ct]);
    }
    if (c < NKC2 - 1) {
      a0 = *(const short8*)(h0 + (c + 1) * 32);
      a1 = *(const short8*)(h1 + (c + 1) * 32);
    }
  }
  const float b3v = b3[0];
#pragma unroll
  for (int rt = 0; rt < 2; ++rt)
#pragma unroll
    for (int q = 0; q < 4; ++q) {
      float s = 0.f;
#pragma unroll
      for (int ct = 0; ct < 10; ++ct) {
        const int col = ct * 16 + l15;
        const float b2c = (col < 150) ? b2[col] : 0.f;
        const float w3c = (col < 150) ? W3[col] : 0.f;
        s = fmaf(fmaxf(acc[rt][ct][q] + b2c, 0.f), w3c, s);
      }
      s += __shfl_xor(s, 1); s += __shfl_xor(s, 2);
      s += __shfl_xor(s, 4); s += __shfl_xor(s, 8);
      if (l15 == 0) {
        const int gr = r0 + w * 32 + rt * 16 + kb * 4 + q;
        if (gr < NP) out[gr] = s + b3v;
      }
    }
}

extern "C" void kernel_launch(void* const* d_in, const int* in_sizes, int n_in,
                              void* d_out, int out_size, void* d_ws, size_t ws_size,
                              hipStream_t stream) {
  const float* M    = (const float*)d_in[0];
  const int*   pidx = (const int*)d_in[1];
  const float* W1   = (const float*)d_in[3];
  const float* b1   = (const float*)d_in[4];
  const float* W2   = (const float*)d_in[5];
  const float* b2   = (const float*)d_in[6];
  const float* W3   = (const float*)d_in[7];
  const float* b3   = (const float*)d_in[8];
  float* out = (float*)d_out;

  const int P = in_sizes[1];
  const int NP = out_size;
  int K = 50;
  for (int k = 1; k <= P; ++k) {
    const long long np = (long long)k * (k - 1) / 2 + (long long)(P - k) * k;
    if (np == (long long)NP) { K = k; break; }
  }
  const int nb = (NP + ROWS - 1) / ROWS;  // k_mlp grid / H1 row capacity base

  // ws: G [P][1216] f32 | AB [2][P][160] f32 | W1ab 2*38*10240 us |
  //     W1c_hi 38*5120 us | W2_hi 5*5120 us | H1 [(nb+1)*128][160] us
  float* G = (float*)d_ws;
  float* AB = G + (size_t)P * DP;
  ushort* W1ab = (ushort*)(AB + (size_t)2 * P * HPAD);
  ushort* W1c_hi = W1ab + (size_t)2 * NKC * WCHU;
  ushort* W2_hi = W1c_hi + (size_t)NKC * WCH1;
  ushort* H1 = W2_hi + (size_t)NKC2 * WCH1;

  const int prepN = 2 * NKC * HPAD * 32 + NKC * HPAD * 32 + NKC2 * HPAD * 32;
  k_prep<<<(prepN + 255) / 256, 256, 0, stream>>>(W1, W2, W1ab, W1c_hi, W2_hi);
  k_gather<<<P, 256, 0, stream>>>(M, pidx, G);
  dim3 gp((P + 31) / 32, 2);
  k_precomp<<<gp, 256, 0, stream>>>(G, W1ab, b1, AB, P);

  if (K == KD && P > KD) {
    const int ND = (P - KD) / TI;                  // dense blocks
    const int headB = (TD + ROWS - 1) / ROWS;      // covers head (+ small overlap)
    k_pair_gen<<<headB, 256, 0, stream>>>(G, W1c_hi, AB, H1, P, K, NP, 0);
    k_pair_dense<<<ND, 256, 0, stream>>>(G, W1c_hi, AB, H1, P, ND);
    const int tail = TD + ND * PB;                 // first pair not covered
    if (tail < NP) {
      const int tb = (NP - tail + ROWS - 1) / ROWS;
      k_pair_gen<<<tb, 256, 0, stream>>>(G, W1c_hi, AB, H1, P, K, NP, tail);
    }
  } else {
    k_pair_gen<<<nb, 256, 0, stream>>>(G, W1c_hi, AB, H1, P, K, NP, 0);
  }
  k_mlp<<<nb, 256, 0, stream>>>(H1, W2_hi, b2, W3, b3, out, NP);
}

// Round 7
// 125.950 us; speedup vs baseline: 2.6943x; 1.7754x over previous
//
#include <hip/hip_runtime.h>

// PairwiseScore round 7: 1-term RNE bf16 X (half the MFMA), TI=5 dense blocks
// (250/256 rows used, 64 rows/wave), head pairs fused as tail blocks of the
// dense grid, prep+gather fused.  Chain: prep_gather -> precomp -> pair -> mlp.
//   h1 = relu(gi@W1a + gj@W1b + (gi.gj)@W1c + b1)   [A/B precomp per mention]
//   out = relu(h1@W2 + b2) @ W3 + b3
// Shapes: M=10000, D=1200(->1216), P=2000, K=50, H=150(->160), NP=98725.

typedef __attribute__((ext_vector_type(8))) short short8;
typedef __attribute__((ext_vector_type(4))) float f32x4;

constexpr int DP    = 1216;      // padded G_DIM (38*32)
constexpr int HPAD  = 160;       // padded hidden
constexpr int NKC   = 38;        // K-chunks of 32 over DP
constexpr int NKC2  = 5;         // K-chunks of 32 over HPAD
constexpr int WCHU  = 10240;     // ushorts per hi+lo W chunk image (precomp)
constexpr int WCH1  = 5120;      // ushorts per hi-only W chunk image
constexpr int ROWS  = 128;       // rows per block (gen path / mlp)
constexpr int KD    = 50;        // compile-time K
constexpr int TI    = 5;         // i's per dense block
constexpr int PB    = TI * KD;   // 250 pairs per dense block
constexpr int NGR   = KD + TI;   // 55 staged G rows
constexpr int TD    = KD * (KD - 1) / 2;  // 1225 head pairs

__device__ __forceinline__ ushort bf16_rne(float x) {
  uint u = __float_as_uint(x);
  u += 0x7FFFu + ((u >> 16) & 1u);
  return (ushort)(u >> 16);
}
__device__ __forceinline__ float bf16f(ushort h) {
  return __uint_as_float((uint)h << 16);
}
__device__ __forceinline__ f32x4 mfma16(short8 a, short8 b, f32x4 c) {
  return __builtin_amdgcn_mfma_f32_16x16x32_bf16(a, b, c, 0, 0, 0);
}
__device__ __forceinline__ void g2lds16(const void* g, void* l) {
  __builtin_amdgcn_global_load_lds(
      (const __attribute__((address_space(1))) void*)g,
      (__attribute__((address_space(3))) void*)l, 16, 0, 0);
}
// stage a 10240B hi-only W chunk
__device__ __forceinline__ void stage_hi(const ushort* gs, ushort* lb,
                                         int w, int lane) {
  const char* g = (const char*)gs + w * 1024 + lane * 16;
  char* l = (char*)lb + w * 1024;
  g2lds16(g, l);
  g2lds16(g + 4096, l + 4096);
  if (w < 2) g2lds16(g + 8192, l + 8192);
}
// stage a 20480B hi+lo chunk (precomp path)
__device__ __forceinline__ void stage_chunk(const ushort* gsrc, ushort* lbuf,
                                            int w, int lane) {
  const char* g = (const char*)gsrc + w * 5120 + lane * 16;
  char* l = (char*)lbuf + w * 5120;
#pragma unroll
  for (int q = 0; q < 5; ++q) g2lds16(g + q * 1024, l + q * 1024);
}
// stage the 55-row x 32-col f32 G slice (chunk c), inverse-XOR source
__device__ __forceinline__ void stage_G5(const float* __restrict__ G, int b0,
                                         int c, float* buf, int w, int lane) {
#pragma unroll
  for (int r = 0; r < 2; ++r) {
    const int slot = r * 256 + w * 64 + lane;
    int row = slot >> 3, grp = slot & 7;
    row = min(row, NGR - 1);
    const float* src =
        G + (size_t)(b0 + row) * DP + c * 32 + ((grp ^ (row & 7)) << 2);
    char* dst = (char*)buf + (r * 256 + w * 64) * 16;  // wave-uniform base
    g2lds16(src, dst);
  }
}
// 1-term: products gi*gj (8 elems) -> bf16 RNE packed
__device__ __forceinline__ short8 mulcvt8(float4 a0, float4 a1, float4 b0,
                                          float4 b1) {
  float p[8] = {a0.x * b0.x, a0.y * b0.y, a0.z * b0.z, a0.w * b0.w,
                a1.x * b1.x, a1.y * b1.y, a1.z * b1.z, a1.w * b1.w};
  uint r[4];
#pragma unroll
  for (int e = 0; e < 4; ++e) {
    uint u0 = __float_as_uint(p[2 * e]);
    uint u1 = __float_as_uint(p[2 * e + 1]);
    u0 += 0x7FFFu + ((u0 >> 16) & 1u);
    u1 += 0x7FFFu + ((u1 >> 16) & 1u);
    r[e] = __builtin_amdgcn_perm(u1, u0, 0x07060302u);
  }
  uint4 h = make_uint4(r[0], r[1], r[2], r[3]);
  return *(short8*)&h;
}
// exact hi/lo split of raw values (precomp path)
__device__ __forceinline__ void split1(const float* a, short8& hi, short8& lo) {
  const float4 a0 = *(const float4*)a, a1 = *(const float4*)(a + 4);
  float p[8] = {a0.x, a0.y, a0.z, a0.w, a1.x, a1.y, a1.z, a1.w};
  uint h[4], l[4];
#pragma unroll
  for (int e = 0; e < 4; ++e) {
    uint u0 = __float_as_uint(p[2 * e]), u1 = __float_as_uint(p[2 * e + 1]);
    float r0 = p[2 * e] - __uint_as_float(u0 & 0xffff0000u);
    float r1 = p[2 * e + 1] - __uint_as_float(u1 & 0xffff0000u);
    h[e] = __builtin_amdgcn_perm(u1, u0, 0x07060302u);
    l[e] = __builtin_amdgcn_perm(__float_as_uint(r1), __float_as_uint(r0),
                                 0x07060302u);
  }
  uint4 hu = make_uint4(h[0], h[1], h[2], h[3]);
  uint4 lu = make_uint4(l[0], l[1], l[2], l[3]);
  hi = *(short8*)&hu; lo = *(short8*)&lu;
}
__device__ __forceinline__ void pair_ij(int r, int K, int NP, int& i, int& j) {
  if (r >= NP) { i = 1; j = 0; return; }
  const int T = K * (K - 1) / 2;
  if (r < T) {
    int ii = (int)((1.0f + sqrtf(1.0f + 8.0f * (float)r)) * 0.5f);
    while (ii * (ii - 1) / 2 > r) --ii;
    while ((ii + 1) * ii / 2 <= r) ++ii;
    i = ii; j = r - ii * (ii - 1) / 2;
  } else {
    const int rp = r - T, q = rp / K;
    i = K + q; j = i - K + (rp - q * K);
  }
}

// ---------- k_prep_gather: fused weight prep + G gather ----------
__global__ void k_prep_gather(const float* __restrict__ W1,
                              const float* __restrict__ W2,
                              const float* __restrict__ M,
                              const int* __restrict__ pidx,
                              ushort* __restrict__ W1ab,
                              ushort* __restrict__ W1c_hi,
                              ushort* __restrict__ W2_hi,
                              float* __restrict__ G, int P) {
  if ((int)blockIdx.x < P) {
    const int i = blockIdx.x;
    const int r = pidx[i];
    const float4* src = reinterpret_cast<const float4*>(M + (size_t)r * 1200);
    float4* dst = reinterpret_cast<float4*>(G + (size_t)i * DP);
    for (int t = threadIdx.x; t < DP / 4; t += blockDim.x)
      dst[t] = (t < 300) ? src[t] : make_float4(0.f, 0.f, 0.f, 0.f);
    return;
  }
  const int NAB = 2 * NKC * HPAD * 32;
  const int NC = NKC * HPAD * 32;
  int idx = (blockIdx.x - P) * 256 + threadIdx.x;
  if (idx < NAB) {
    int s = idx / NC, r1 = idx % NC;
    int c = r1 / (HPAD * 32), r2 = r1 % (HPAD * 32);
    int col = r2 >> 5, kk = r2 & 31;
    int k = c * 32 + kk;
    float v = (k < 1200 && col < 150) ? W1[((size_t)s * 1200 + k) * 150 + col] : 0.f;
    ushort h = bf16_rne(v);
    ushort l = bf16_rne(v - bf16f(h));
    size_t base = (size_t)(s * NKC + c) * WCHU;
    int i0 = (col * 32 + kk) ^ ((col & 7) << 3);
    W1ab[base + i0] = h;
    W1ab[base + i0 + 5120] = l;
  } else if (idx < NAB + NC) {
    int r1 = idx - NAB;
    int c = r1 / (HPAD * 32), r2 = r1 % (HPAD * 32);
    int col = r2 >> 5, kk = r2 & 31;
    int k = c * 32 + kk;
    float v = (k < 1200 && col < 150)
                  ? W1[((size_t)2 * 1200 + k) * 150 + col] : 0.f;
    int i0 = (col * 32 + kk) ^ ((col & 7) << 3);
    W1c_hi[(size_t)c * WCH1 + i0] = bf16_rne(v);
  } else {
    int r1 = idx - NAB - NC;
    if (r1 < NKC2 * HPAD * 32) {
      int c = r1 / (HPAD * 32), r2 = r1 % (HPAD * 32);
      int col = r2 >> 5, kk = r2 & 31;
      int k = c * 32 + kk;
      float v = (k < 150 && col < 150) ? W2[(size_t)k * 150 + col] : 0.f;
      int i0 = (col * 32 + kk) ^ ((col & 7) << 3);
      W2_hi[(size_t)c * WCH1 + i0] = bf16_rne(v);
    }
  }
}

// ---------- k_precomp: AB[slab][r][col] = G[r]@W1slab (+b1 if slab0), 3-term ----------
__global__ __launch_bounds__(256, 4) void k_precomp(
    const float* __restrict__ G, const ushort* __restrict__ W1ab,
    const float* __restrict__ b1, float* __restrict__ AB, int P) {
  __shared__ __align__(16) ushort Wb[2][WCHU];
  const int tid = threadIdx.x, lane = tid & 63, w = tid >> 6;
  const int l15 = lane & 15, kb = lane >> 4;
  const int rt = w & 1, ch = w >> 1;
  const int r0 = blockIdx.x * 32;
  const int slab = blockIdx.y;
  const ushort* wsrc = W1ab + (size_t)slab * NKC * WCHU;

  const int row = min(r0 + rt * 16 + l15, P - 1);
  const float* g = G + (size_t)row * DP + kb * 8;
  const int lbase = (l15 * 32 + kb * 8) ^ ((l15 & 7) << 3);

  f32x4 acc[5];
#pragma unroll
  for (int b = 0; b < 5; ++b) acc[b] = (f32x4)(0.f);

  stage_chunk(wsrc, Wb[0], w, lane);
  short8 ah, al;
  split1(g, ah, al);

  for (int c = 0; c < NKC; ++c) {
    __syncthreads();
    if (c < NKC - 1)
      stage_chunk(wsrc + (size_t)(c + 1) * WCHU, Wb[(c + 1) & 1], w, lane);
    const ushort* wb = Wb[c & 1];
#pragma unroll
    for (int ct = 0; ct < 5; ++ct) {
      const int ob = (ch * 5 + ct) * 512 + lbase;
      const short8 bh = *(const short8*)&wb[ob];
      const short8 bl = *(const short8*)&wb[ob + 5120];
      acc[ct] = mfma16(ah, bh, acc[ct]);
      acc[ct] = mfma16(al, bh, acc[ct]);
      acc[ct] = mfma16(ah, bl, acc[ct]);
    }
    if (c < NKC - 1) split1(g + (c + 1) * 32, ah, al);
  }
  float* outp = AB + (size_t)slab * P * HPAD;
#pragma unroll
  for (int q = 0; q < 4; ++q) {
    const int r = r0 + rt * 16 + kb * 4 + q;
    if (r < P) {
#pragma unroll
      for (int ct = 0; ct < 5; ++ct) {
        const int col = (ch * 5 + ct) * 16 + l15;
        float v = acc[ct][q];
        if (slab == 0 && col < 150) v += b1[col];
        outp[(size_t)r * HPAD + col] = v;
      }
    }
  }
}

// ---------- k_pair: dense (blocks < ND) + gen head (blocks >= ND) ----------
__global__ __launch_bounds__(256, 2) void k_pair(
    const float* __restrict__ G, const ushort* __restrict__ W1c_hi,
    const float* __restrict__ AB, ushort* __restrict__ H1,
    int P, int K, int NP, int ND, int wmax) {
  __shared__ __align__(16) ushort Wb[2][WCH1];   // 20480 B
  __shared__ __align__(16) float Gs[2][2048];    // 16384 B (512 slots x 16B)
  __shared__ int tI[ROWS], tJ[ROWS];
  const int tid = threadIdx.x, lane = tid & 63, w = tid >> 6;
  const int l15 = lane & 15, kb = lane >> 4;
  const int lswz = (l15 * 32 + kb * 8) ^ ((l15 & 7) << 3);

  if ((int)blockIdx.x < ND) {
    // ---------------- dense: TI=5 i's, 250 pairs, 4 rt x 4 waves ----------------
    const int q8 = ND >> 3, r8 = ND & 7;
    const int xcd = blockIdx.x & 7, sidx = blockIdx.x >> 3;
    const int bid = (xcd < r8) ? xcd * (q8 + 1) + sidx
                               : r8 * (q8 + 1) + (xcd - r8) * q8 + sidx;
    const int i0 = KD + bid * TI;
    const int b0 = i0 - KD;

    int sI0[4], sI1[4], sJ0[4], sJ1[4];
#pragma unroll
    for (int rt = 0; rt < 4; ++rt) {
      const int q = min(w * 64 + rt * 16 + l15, PB - 1);
      const int li = KD + q / KD, lj = q / KD + q % KD;
      sI0[rt] = li * 8 + ((2 * kb) ^ (li & 7));
      sI1[rt] = li * 8 + ((2 * kb + 1) ^ (li & 7));
      sJ0[rt] = lj * 8 + ((2 * kb) ^ (lj & 7));
      sJ1[rt] = lj * 8 + ((2 * kb + 1) ^ (lj & 7));
    }

    f32x4 acc[4][10];
#pragma unroll
    for (int a = 0; a < 4; ++a)
#pragma unroll
      for (int b = 0; b < 10; ++b) acc[a][b] = (f32x4)(0.f);

    stage_G5(G, b0, 0, Gs[0], w, lane);
    stage_hi(W1c_hi, Wb[0], w, lane);
    __syncthreads();

#pragma unroll 2
    for (int c = 0; c < NKC; ++c) {
      if (c) __syncthreads();
      if (c < NKC - 1) {
        stage_G5(G, b0, c + 1, Gs[(c + 1) & 1], w, lane);
        stage_hi(W1c_hi + (size_t)(c + 1) * WCH1, Wb[(c + 1) & 1], w, lane);
      }
      const float4* gp = (const float4*)Gs[c & 1];
      const ushort* wb = Wb[c & 1];
      short8 a[4];
#pragma unroll
      for (int rt = 0; rt < 4; ++rt)
        a[rt] = mulcvt8(gp[sI0[rt]], gp[sI1[rt]], gp[sJ0[rt]], gp[sJ1[rt]]);
#pragma unroll
      for (int ct = 0; ct < 10; ++ct) {
        const short8 bh = *(const short8*)&wb[ct * 512 + lswz];
        acc[0][ct] = mfma16(a[0], bh, acc[0][ct]);
        acc[1][ct] = mfma16(a[1], bh, acc[1][ct]);
        acc[2][ct] = mfma16(a[2], bh, acc[2][ct]);
        acc[3][ct] = mfma16(a[3], bh, acc[3][ct]);
      }
    }

    // epilogue: h1 = relu(acc + A[i] + B[j]) -> H1 row TD + bid*PB + rr
#pragma unroll
    for (int rt = 0; rt < 4; ++rt)
#pragma unroll
      for (int qq = 0; qq < 4; ++qq) {
        const int rr = w * 64 + rt * 16 + kb * 4 + qq;
        if (rr < PB) {
          const int ii = i0 + rr / KD;
          const int jj = ii - KD + rr % KD;
          const float* Ar = AB + (size_t)ii * HPAD;
          const float* Br = AB + ((size_t)P + jj) * HPAD;
          ushort* hrow = H1 + (size_t)(TD + bid * PB + rr) * HPAD;
#pragma unroll
          for (int ct = 0; ct < 10; ++ct) {
            const int col = ct * 16 + l15;
            const float v = acc[rt][ct][qq] + Ar[col] + Br[col];
            hrow[col] = bf16_rne(fmaxf(v, 0.f));
          }
        }
      }
  } else {
    // ---------------- gen: gathered pairs, writes only rows < wmax ----------------
    const int r0 = ((int)blockIdx.x - ND) * ROWS;
    if (tid < ROWS) {
      int i, j;
      pair_ij(r0 + tid, K, NP, i, j);
      tI[tid] = i; tJ[tid] = j;
    }
    stage_hi(W1c_hi, Wb[0], w, lane);
    __syncthreads();

    const int rowA = w * 32 + l15, rowB = rowA + 16;
    const float* gi0 = G + (size_t)tI[rowA] * DP + kb * 8;
    const float* gj0 = G + (size_t)tJ[rowA] * DP + kb * 8;
    const float* gi1 = G + (size_t)tI[rowB] * DP + kb * 8;
    const float* gj1 = G + (size_t)tJ[rowB] * DP + kb * 8;

    f32x4 acc[2][10];
#pragma unroll
    for (int a = 0; a < 2; ++a)
#pragma unroll
      for (int b = 0; b < 10; ++b) acc[a][b] = (f32x4)(0.f);

    float4 x00 = *(const float4*)gi0, x01 = *(const float4*)(gi0 + 4);
    float4 y00 = *(const float4*)gj0, y01 = *(const float4*)(gj0 + 4);
    float4 x10 = *(const float4*)gi1, x11 = *(const float4*)(gi1 + 4);
    float4 y10 = *(const float4*)gj1, y11 = *(const float4*)(gj1 + 4);

#pragma unroll 2
    for (int c = 0; c < NKC; ++c) {
      if (c) __syncthreads();
      if (c < NKC - 1)
        stage_hi(W1c_hi + (size_t)(c + 1) * WCH1, Wb[(c + 1) & 1], w, lane);
      const short8 a0 = mulcvt8(x00, x01, y00, y01);
      const short8 a1 = mulcvt8(x10, x11, y10, y11);
      if (c < NKC - 1) {
        const int cn = c + 1;
        x00 = *(const float4*)(gi0 + cn * 32); x01 = *(const float4*)(gi0 + cn * 32 + 4);
        y00 = *(const float4*)(gj0 + cn * 32); y01 = *(const float4*)(gj0 + cn * 32 + 4);
        x10 = *(const float4*)(gi1 + cn * 32); x11 = *(const float4*)(gi1 + cn * 32 + 4);
        y10 = *(const float4*)(gj1 + cn * 32); y11 = *(const float4*)(gj1 + cn * 32 + 4);
      }
      const ushort* wb = Wb[c & 1];
#pragma unroll
      for (int ct = 0; ct < 10; ++ct) {
        const short8 bh = *(const short8*)&wb[ct * 512 + lswz];
        acc[0][ct] = mfma16(a0, bh, acc[0][ct]);
        acc[1][ct] = mfma16(a1, bh, acc[1][ct]);
      }
    }

#pragma unroll
    for (int rt = 0; rt < 2; ++rt)
#pragma unroll
      for (int q = 0; q < 4; ++q) {
        const int rr = w * 32 + rt * 16 + kb * 4 + q;
        const int gr = r0 + rr;
        if (gr < wmax) {
          const float* Ar = AB + (size_t)tI[rr] * HPAD;
          const float* Br = AB + ((size_t)P + tJ[rr]) * HPAD;
          ushort* hrow = H1 + (size_t)gr * HPAD;
#pragma unroll
          for (int ct = 0; ct < 10; ++ct) {
            const int col = ct * 16 + l15;
            const float v = acc[rt][ct][q] + Ar[col] + Br[col];
            hrow[col] = bf16_rne(fmaxf(v, 0.f));
          }
        }
      }
  }
}

// ---------- k_mlp: out = relu(H1@W2 + b2) @ W3 + b3 (hi-only W2) ----------
__global__ __launch_bounds__(256, 3) void k_mlp(
    const ushort* __restrict__ H1, const ushort* __restrict__ W2_hi,
    const float* __restrict__ b2, const float* __restrict__ W3,
    const float* __restrict__ b3, float* __restrict__ out, int NP) {
  __shared__ __align__(16) ushort Wb[2][WCH1];
  const int tid = threadIdx.x, lane = tid & 63, w = tid >> 6;
  const int l15 = lane & 15, kb = lane >> 4;
  const int r0 = blockIdx.x * ROWS;
  const int lswz = (l15 * 32 + kb * 8) ^ ((l15 & 7) << 3);

  const ushort* h0 = H1 + (size_t)(r0 + w * 32 + l15) * HPAD + kb * 8;
  const ushort* h1 = H1 + (size_t)(r0 + w * 32 + 16 + l15) * HPAD + kb * 8;

  f32x4 acc[2][10];
#pragma unroll
  for (int a = 0; a < 2; ++a)
#pragma unroll
    for (int b = 0; b < 10; ++b) acc[a][b] = (f32x4)(0.f);

  stage_hi(W2_hi, Wb[0], w, lane);
  short8 a0 = *(const short8*)h0;
  short8 a1 = *(const short8*)h1;

#pragma unroll
  for (int c = 0; c < NKC2; ++c) {
    __syncthreads();
    if (c < NKC2 - 1)
      stage_hi(W2_hi + (size_t)(c + 1) * WCH1, Wb[(c + 1) & 1], w, lane);
    const ushort* wb = Wb[c & 1];
#pragma unroll
    for (int ct = 0; ct < 10; ++ct) {
      const short8 bh = *(const short8*)&wb[ct * 512 + lswz];
      acc[0][ct] = mfma16(a0, bh, acc[0][ct]);
      acc[1][ct] = mfma16(a1, bh, acc[1][ct]);
    }
    if (c < NKC2 - 1) {
      a0 = *(const short8*)(h0 + (c + 1) * 32);
      a1 = *(const short8*)(h1 + (c + 1) * 32);
    }
  }
  const float b3v = b3[0];
#pragma unroll
  for (int rt = 0; rt < 2; ++rt)
#pragma unroll
    for (int q = 0; q < 4; ++q) {
      float s = 0.f;
#pragma unroll
      for (int ct = 0; ct < 10; ++ct) {
        const int col = ct * 16 + l15;
        const float b2c = (col < 150) ? b2[col] : 0.f;
        const float w3c = (col < 150) ? W3[col] : 0.f;
        s = fmaf(fmaxf(acc[rt][ct][q] + b2c, 0.f), w3c, s);
      }
      s += __shfl_xor(s, 1); s += __shfl_xor(s, 2);
      s += __shfl_xor(s, 4); s += __shfl_xor(s, 8);
      if (l15 == 0) {
        const int gr = r0 + w * 32 + rt * 16 + kb * 4 + q;
        if (gr < NP) out[gr] = s + b3v;
      }
    }
}

extern "C" void kernel_launch(void* const* d_in, const int* in_sizes, int n_in,
                              void* d_out, int out_size, void* d_ws, size_t ws_size,
                              hipStream_t stream) {
  const float* M    = (const float*)d_in[0];
  const int*   pidx = (const int*)d_in[1];
  const float* W1   = (const float*)d_in[3];
  const float* b1   = (const float*)d_in[4];
  const float* W2   = (const float*)d_in[5];
  const float* b2   = (const float*)d_in[6];
  const float* W3   = (const float*)d_in[7];
  const float* b3   = (const float*)d_in[8];
  float* out = (float*)d_out;

  const int P = in_sizes[1];
  const int NP = out_size;
  int K = 50;
  for (int k = 1; k <= P; ++k) {
    const long long np = (long long)k * (k - 1) / 2 + (long long)(P - k) * k;
    if (np == (long long)NP) { K = k; break; }
  }
  const int nb = (NP + ROWS - 1) / ROWS;

  // ws: G [P][1216] f32 | AB [2][P][160] f32 | W1ab 2*38*10240 us |
  //     W1c_hi 38*5120 us | W2_hi 5*5120 us | H1 [nb*128][160] us
  float* G = (float*)d_ws;
  float* AB = G + (size_t)P * DP;
  ushort* W1ab = (ushort*)(AB + (size_t)2 * P * HPAD);
  ushort* W1c_hi = W1ab + (size_t)2 * NKC * WCHU;
  ushort* W2_hi = W1c_hi + (size_t)NKC * WCH1;
  ushort* H1 = W2_hi + (size_t)NKC2 * WCH1;

  const int prepN = (2 * NKC + NKC + NKC2) * HPAD * 32;
  const int prepB = (prepN + 255) / 256;
  k_prep_gather<<<P + prepB, 256, 0, stream>>>(W1, W2, M, pidx, W1ab, W1c_hi,
                                               W2_hi, G, P);
  dim3 gp((P + 31) / 32, 2);
  k_precomp<<<gp, 256, 0, stream>>>(G, W1ab, b1, AB, P);

  int ND = 0, wmax = NP;
  if (K == KD && P > KD && (P - KD) % TI == 0) {
    ND = (P - KD) / TI;   // 390 dense blocks
    wmax = TD;            // gen blocks write only head rows
  }
  const int genB = (wmax + ROWS - 1) / ROWS;
  k_pair<<<ND + genB, 256, 0, stream>>>(G, W1c_hi, AB, H1, P, K, NP, ND, wmax);
  k_mlp<<<nb, 256, 0, stream>>>(H1, W2_hi, b2, W3, b3, out, NP);
}